// Round 2
// baseline (756.367 us; speedup 1.0000x reference)
//
#include <hip/hip_runtime.h>
#include <hip/hip_bf16.h>

#define NN 51200
#define EE 819200
#define BB 64
#define GRID 256
#define TPB_TILES 25    // (EE/128) / GRID = 6400/256

typedef __attribute__((ext_vector_type(8))) short short8;
typedef __attribute__((ext_vector_type(4))) float f32x4;

__device__ __forceinline__ ushort f2bf(float f) {
    unsigned int u = __float_as_uint(f);
    unsigned int r = (u + 0x7FFFu + ((u >> 16) & 1u)) >> 16;   // RNE, finite inputs
    return (ushort)r;
}

// D.lo16 = bf16(lo), D.hi16 = bf16(hi)  (RNE)
__device__ __forceinline__ unsigned int cvt_pk_bf16(float lo, float hi) {
    unsigned int r;
    asm("v_cvt_pk_bf16_f32 %0, %1, %2" : "=v"(r) : "v"(lo), "v"(hi));
    return r;
}

// ---------------- weight prep: fragment-ordered bf16 ----------------
// Wp[((ks*4+g)*N + n)*8 + i] = W[(ks*32 + g*8 + i)*N + n]
__global__ void prep_weights(const float* __restrict__ gW1, const float* __restrict__ gW2,
                             const float* __restrict__ lW1,
                             ushort* __restrict__ W1p, ushort* __restrict__ W2p,
                             ushort* __restrict__ L1p) {
    int tid = threadIdx.x;
    for (int idx = tid; idx < 128 * 128; idx += 256) {          // gW1 [128][128]
        int i = idx & 7, n = (idx >> 3) & 127, q = idx >> 10;
        int k = (q >> 2) * 32 + (q & 3) * 8 + i;
        W1p[idx] = f2bf(gW1[k * 128 + n]);
    }
    for (int idx = tid; idx < 128 * 64; idx += 256) {           // gW2 [128][64]
        int i = idx & 7, n = (idx >> 3) & 63, q = idx >> 9;
        int k = (q >> 2) * 32 + (q & 3) * 8 + i;
        W2p[idx] = f2bf(gW2[k * 64 + n]);
    }
    for (int idx = tid; idx < 256 * 128; idx += 256) {          // lW1 [256][128]
        int i = idx & 7, n = (idx >> 3) & 127, q = idx >> 10;
        int k = (q >> 2) * 32 + (q & 3) * 8 + i;
        L1p[idx] = f2bf(lW1[k * 128 + n]);
    }
}

// ---------------- global conv fused with pooling ----------------
// pooled[b][c] = sum_edges e[dst] * (MLP(concat(x[dst],x[src]))[c]), b = batch[dst]
__global__ __launch_bounds__(512, 2) void global_conv(
        const float* __restrict__ x, const int* __restrict__ eidx,
        const ushort* __restrict__ W1p, const ushort* __restrict__ W2p,
        const float* __restrict__ gb1, const float* __restrict__ gb2,
        const float* __restrict__ e, const int* __restrict__ batch,
        float* __restrict__ pooled) {
    __shared__ __attribute__((aligned(16))) ushort sW1[128 * 128];   // 32 KB
    __shared__ __attribute__((aligned(16))) ushort sW2[128 * 64];    // 16 KB
    __shared__ __attribute__((aligned(16))) ushort sHid[8 * 16 * 128]; // 32 KB, per-wave scratch
    __shared__ float sPool[BB * 64];                                  // 16 KB

    const int tid = threadIdx.x;
    {   // stage fragment-ordered weights + zero pooled accumulator
        const uint4* s1 = (const uint4*)W1p; uint4* d1 = (uint4*)sW1;
        for (int c = tid; c < 2048; c += 512) d1[c] = s1[c];
        const uint4* s2 = (const uint4*)W2p; uint4* d2 = (uint4*)sW2;
        for (int c = tid; c < 1024; c += 512) d2[c] = s2[c];
        for (int c = tid; c < BB * 64; c += 512) sPool[c] = 0.f;
    }
    __syncthreads();

    const int w = tid >> 6, l = tid & 63, lr = l & 15, lg = l >> 4;
    const int swz = (lr & 7) << 3;                 // element-index XOR (bits 3..5)
    ushort* myHid = sHid + (w * 16 + lr) * 128;    // lane's edge-row scratch

    // biases held in regs; folded into MFMA C-init
    float b1r[8][4];
#pragma unroll
    for (int t = 0; t < 8; ++t)
#pragma unroll
        for (int i = 0; i < 4; ++i) b1r[t][i] = gb1[t * 16 + lg * 4 + i];
    float b2r[4];
#pragma unroll
    for (int t2 = 0; t2 < 4; ++t2) b2r[t2] = gb2[t2 * 16 + lr];

    // preload tile 0 (edge idx + raw fp32 gather)
    int dstc = eidx[EE + blockIdx.x * 128 + w * 16 + lr];
    int srcc = eidx[blockIdx.x * 128 + w * 16 + lr];
    float4 raw[8];
#pragma unroll
    for (int ks = 0; ks < 4; ++ks) {
        const float* base = x + (long)(ks < 2 ? dstc : srcc) * 64 + (ks & 1) * 32 + lg * 8;
        raw[2 * ks]     = *(const float4*)base;
        raw[2 * ks + 1] = *(const float4*)(base + 4);
    }

    for (int it = 0; it < TPB_TILES; ++it) {
        // cvt raw -> A-frags (lane = edge row lr, k-chunk ks*32+lg*8)
        short8 ha[4];
#pragma unroll
        for (int ks = 0; ks < 4; ++ks) {
            union { short8 s; unsigned int u[4]; } tmp;
            tmp.u[0] = cvt_pk_bf16(raw[2 * ks].x,     raw[2 * ks].y);
            tmp.u[1] = cvt_pk_bf16(raw[2 * ks].z,     raw[2 * ks].w);
            tmp.u[2] = cvt_pk_bf16(raw[2 * ks + 1].x, raw[2 * ks + 1].y);
            tmp.u[3] = cvt_pk_bf16(raw[2 * ks + 1].z, raw[2 * ks + 1].w);
            ha[ks] = tmp.s;
        }
        // epilogue meta for current tile (issued early, hidden under GEMM1)
        float ew[4]; int bb[4];
#pragma unroll
        for (int i = 0; i < 4; ++i) {
            int d4 = __shfl(dstc, lg * 4 + i, 64);
            ew[i] = e[d4];
            bb[i] = batch[d4];
        }
        // GEMM1 (swapped): D = W1^T @ H^T -> lane holds Hid[edge=lr][chan t*16+lg*4+i]
        f32x4 acc[8];
#pragma unroll
        for (int t = 0; t < 8; ++t) {
            f32x4 a; a[0] = b1r[t][0]; a[1] = b1r[t][1]; a[2] = b1r[t][2]; a[3] = b1r[t][3];
            acc[t] = a;
        }
#pragma unroll
        for (int ks = 0; ks < 4; ++ks)
#pragma unroll
            for (int t = 0; t < 8; ++t) {
                short8 wf = *(const short8*)(sW1 + ((ks * 4 + lg) * 128 + t * 16 + lr) * 8);
                acc[t] = __builtin_amdgcn_mfma_f32_16x16x32_bf16(wf, ha[ks], acc[t], 0, 0, 0);
            }
        // software-pipeline: issue next tile's idx + gather now
        int dstn = dstc, srcn = srcc;
        if (it + 1 < TPB_TILES) {
            const int tn = blockIdx.x + (it + 1) * GRID;
            dstn = eidx[EE + tn * 128 + w * 16 + lr];
            srcn = eidx[tn * 128 + w * 16 + lr];
#pragma unroll
            for (int ks = 0; ks < 4; ++ks) {
                const float* base = x + (long)(ks < 2 ? dstn : srcn) * 64 + (ks & 1) * 32 + lg * 8;
                raw[2 * ks]     = *(const float4*)base;
                raw[2 * ks + 1] = *(const float4*)(base + 4);
            }
        }
        // relu + pack + swizzled per-wave transpose (no barriers: own-wave region)
#pragma unroll
        for (int t = 0; t < 8; ++t) {
            uint2 v;
            v.x = cvt_pk_bf16(fmaxf(acc[t][0], 0.f), fmaxf(acc[t][1], 0.f));
            v.y = cvt_pk_bf16(fmaxf(acc[t][2], 0.f), fmaxf(acc[t][3], 0.f));
            *(uint2*)(myHid + ((t * 16 + lg * 4) ^ swz)) = v;
        }
        short8 a2[4];
#pragma unroll
        for (int k2 = 0; k2 < 4; ++k2)
            a2[k2] = *(const short8*)(myHid + ((k2 * 32 + lg * 8) ^ swz));
        // GEMM2 (standard): M[edge][chan], lane holds rows lg*4+i, cols t2*16+lr
        f32x4 acc2[4];
#pragma unroll
        for (int t2 = 0; t2 < 4; ++t2) {
            f32x4 a; a[0] = b2r[t2]; a[1] = b2r[t2]; a[2] = b2r[t2]; a[3] = b2r[t2];
            acc2[t2] = a;
        }
#pragma unroll
        for (int k2 = 0; k2 < 4; ++k2)
#pragma unroll
            for (int t2 = 0; t2 < 4; ++t2) {
                short8 wf = *(const short8*)(sW2 + ((k2 * 4 + lg) * 64 + t2 * 16 + lr) * 8);
                acc2[t2] = __builtin_amdgcn_mfma_f32_16x16x32_bf16(a2[k2], wf, acc2[t2], 0, 0, 0);
            }
        // fused pooling: LDS atomic accumulate e[dst]*m into pooled[batch[dst]]
#pragma unroll
        for (int t2 = 0; t2 < 4; ++t2)
#pragma unroll
            for (int i = 0; i < 4; ++i)
                atomicAdd(&sPool[bb[i] * 64 + t2 * 16 + lr], acc2[t2][i] * ew[i]);
        dstc = dstn; srcc = srcn;
    }
    __syncthreads();
#pragma unroll
    for (int j = 0; j < 8; ++j) {
        int idx = tid * 8 + j;
        atomicAdd(&pooled[idx], sPool[idx]);
    }
}

// ---------------- xl[n] = bf16(concat(x[n], pooled[batch[n]])) ----------------
__global__ void build_xl(const float* __restrict__ x, const float* __restrict__ pooled,
                         const int* __restrict__ batch, ushort* __restrict__ xl) {
    int idx = blockIdx.x * 256 + threadIdx.x;     // < N*16
    int node = idx >> 4, ch = idx & 15;
    const float4* base;
    if (ch < 8) base = reinterpret_cast<const float4*>(x + (long)node * 64 + ch * 8);
    else        base = reinterpret_cast<const float4*>(pooled + (long)batch[node] * 64 + (ch - 8) * 8);
    float4 f0 = base[0], f1 = base[1];
    union { short8 s; unsigned int u[4]; } v;
    v.u[0] = cvt_pk_bf16(f0.x, f0.y);
    v.u[1] = cvt_pk_bf16(f0.z, f0.w);
    v.u[2] = cvt_pk_bf16(f1.x, f1.y);
    v.u[3] = cvt_pk_bf16(f1.z, f1.w);
    *reinterpret_cast<short8*>(xl + (long)node * 128 + ch * 8) = v.s;
}

// ---------------- local conv: out[dst] += relu(h@lW1+b1)@lW2 + b2, h in regs ----------------
__global__ __launch_bounds__(512, 2) void local_conv(
        const ushort* __restrict__ xl, const int* __restrict__ eidx,
        const ushort* __restrict__ L1p, const float* __restrict__ lb1,
        const float* __restrict__ lW2, const float* __restrict__ lb2,
        float* __restrict__ out) {
    __shared__ __attribute__((aligned(16))) ushort sW[256 * 128];    // 64 KB
    const int tid = threadIdx.x;
    {
        const uint4* s1 = (const uint4*)L1p; uint4* d1 = (uint4*)sW;
        for (int c = tid; c < 4096; c += 512) d1[c] = s1[c];
    }
    __syncthreads();

    const int w = tid >> 6, l = tid & 63, lr = l & 15, lg = l >> 4;
    float b1r[8][4], w2r[8][4];
#pragma unroll
    for (int t = 0; t < 8; ++t)
#pragma unroll
        for (int i = 0; i < 4; ++i) {
            b1r[t][i] = lb1[t * 16 + lg * 4 + i];
            w2r[t][i] = lW2[t * 16 + lg * 4 + i];
        }
    const float b2v = lb2[0];

    int dstc = eidx[EE + blockIdx.x * 128 + w * 16 + lr];
    int srcc = eidx[blockIdx.x * 128 + w * 16 + lr];
    short8 ha[8];
#pragma unroll
    for (int ks = 0; ks < 8; ++ks)
        ha[ks] = *(const short8*)(xl + (long)(ks < 4 ? dstc : srcc) * 128 + (ks & 3) * 32 + lg * 8);

    for (int it = 0; it < TPB_TILES; ++it) {
        // GEMM1 (swapped): lane holds Hid[edge=lr][chan t*16+lg*4+i]
        f32x4 acc[8];
#pragma unroll
        for (int t = 0; t < 8; ++t) {
            f32x4 a; a[0] = b1r[t][0]; a[1] = b1r[t][1]; a[2] = b1r[t][2]; a[3] = b1r[t][3];
            acc[t] = a;
        }
#pragma unroll
        for (int ks = 0; ks < 8; ++ks)
#pragma unroll
            for (int t = 0; t < 8; ++t) {
                short8 wf = *(const short8*)(sW + ((ks * 4 + lg) * 128 + t * 16 + lr) * 8);
                acc[t] = __builtin_amdgcn_mfma_f32_16x16x32_bf16(wf, ha[ks], acc[t], 0, 0, 0);
            }
        // prefetch next tile
        int dstn = dstc, srcn = srcc;
        short8 han[8];
        const bool hasnext = (it + 1 < TPB_TILES);
        if (hasnext) {
            const int tn = blockIdx.x + (it + 1) * GRID;
            dstn = eidx[EE + tn * 128 + w * 16 + lr];
            srcn = eidx[tn * 128 + w * 16 + lr];
#pragma unroll
            for (int ks = 0; ks < 8; ++ks)
                han[ks] = *(const short8*)(xl + (long)(ks < 4 ? dstn : srcn) * 128 + (ks & 3) * 32 + lg * 8);
        }
        // relu + dot(w2) in regs, reduce across the 4 lg groups
        float part = 0.f;
#pragma unroll
        for (int t = 0; t < 8; ++t)
#pragma unroll
            for (int i = 0; i < 4; ++i)
                part += fmaxf(acc[t][i], 0.f) * w2r[t][i];
        part += __shfl_xor(part, 16, 64);
        part += __shfl_xor(part, 32, 64);
        if (l < 16) atomicAdd(&out[dstc], part + b2v);
        dstc = dstn; srcc = srcn;
        if (hasnext) {
#pragma unroll
            for (int ks = 0; ks < 8; ++ks) ha[ks] = han[ks];
        }
    }
}

extern "C" void kernel_launch(void* const* d_in, const int* in_sizes, int n_in,
                              void* d_out, int out_size, void* d_ws, size_t ws_size,
                              hipStream_t stream) {
    const float* x   = (const float*)d_in[0];
    const float* e   = (const float*)d_in[1];
    const int*   ei  = (const int*)d_in[2];
    const int*   bat = (const int*)d_in[3];
    const float* gW1 = (const float*)d_in[4];
    const float* gb1 = (const float*)d_in[5];
    const float* gW2 = (const float*)d_in[6];
    const float* gb2 = (const float*)d_in[7];
    const float* lW1 = (const float*)d_in[8];
    const float* lb1 = (const float*)d_in[9];
    const float* lW2 = (const float*)d_in[10];
    const float* lb2 = (const float*)d_in[11];

    char* ws = (char*)d_ws;
    ushort* W1p    = (ushort*)(ws);                    // 32768 B
    ushort* W2p    = (ushort*)(ws + 32768);            // 16384 B
    ushort* L1p    = (ushort*)(ws + 49152);            // 65536 B
    float*  pooled = (float*)(ws + 114688);            // 16384 B
    ushort* xl     = (ushort*)(ws + 131072);           // N*128*2 = 13107200 B

    hipMemsetAsync(pooled, 0, 16384, stream);
    hipMemsetAsync(d_out, 0, (size_t)out_size * sizeof(float), stream);

    prep_weights<<<1, 256, 0, stream>>>(gW1, gW2, lW1, W1p, W2p, L1p);
    global_conv<<<GRID, 512, 0, stream>>>(x, ei, W1p, W2p, gb1, gb2, e, bat, pooled);
    build_xl<<<NN * 16 / 256, 256, 0, stream>>>(x, pooled, bat, xl);
    local_conv<<<GRID, 512, 0, stream>>>(xl, ei, L1p, lb1, lW2, lb2, (float*)d_out);
}

// Round 3
// 712.152 us; speedup vs baseline: 1.0621x; 1.0621x over previous
//
#include <hip/hip_runtime.h>
#include <hip/hip_bf16.h>

#define NN 51200
#define EE 819200
#define BB 64
#define NS 32

typedef __attribute__((ext_vector_type(8))) short short8;
typedef __attribute__((ext_vector_type(4))) float f32x4;

__device__ __forceinline__ ushort f2bf(float f) {
    unsigned int u = __float_as_uint(f);
    unsigned int r = (u + 0x7FFFu + ((u >> 16) & 1u)) >> 16;   // RNE, finite inputs
    return (ushort)r;
}
__device__ __forceinline__ unsigned int cvt_pk_bf16(float lo, float hi) {
    unsigned int r;
    asm("v_cvt_pk_bf16_f32 %0, %1, %2" : "=v"(r) : "v"(lo), "v"(hi));
    return r;
}
__device__ __forceinline__ float bf2f(ushort u) {
    return __uint_as_float(((unsigned int)u) << 16);
}

// ---------------- weight prep ----------------
// W1p: frag-ordered [gW1[0:64] | gW1[64:128]] viewed as [64 k][256 c]
// L1p: frag-ordered [lW1[0:64] | lW1[128:192]] viewed as [64 k][256 c]
// Wp[(q*256 + c)*8 + i] = Wcat[(q>>2)*32 + (q&3)*8 + i][c]
__global__ void prep_weights(const float* __restrict__ gW1, const float* __restrict__ lW1,
                             ushort* __restrict__ W1p, ushort* __restrict__ L1p) {
    int tid = threadIdx.x;
    for (int idx = tid; idx < 64 * 256; idx += 512) {
        int i = idx & 7, c = (idx >> 3) & 255, q = idx >> 11;
        int k = (q >> 2) * 32 + (q & 3) * 8 + i;
        W1p[idx] = f2bf(c < 128 ? gW1[k * 128 + c] : gW1[(64 + k) * 128 + (c - 128)]);
        L1p[idx] = f2bf(c < 128 ? lW1[k * 128 + c] : lW1[(128 + k) * 128 + (c - 128)]);
    }
}

// ---------------- node-table GEMM: out[n][0:256] = bf16( x[n]@Wcat + bias_fold + T12[batch[n]] ) ----------------
// swapped MFMA: lane holds node = l&15, channels t*16 + (l>>4)*4 + i
__global__ __launch_bounds__(512) void pq_gemm(
        const float* __restrict__ x, const ushort* __restrict__ Wp,
        const float* __restrict__ bias1,                 // folded into ch<128 half
        const float* __restrict__ T12,                   // nullptr for global pass
        const int* __restrict__ batch,
        ushort* __restrict__ out) {
    const int tid = threadIdx.x;
    const int w = tid >> 6, l = tid & 63, lr = l & 15, lg = l >> 4;
    const int node = blockIdx.x * 128 + w * 16 + lr;

    short8 xa[2];
#pragma unroll
    for (int ks = 0; ks < 2; ++ks) {
        const float4* bp = reinterpret_cast<const float4*>(x + (long)node * 64 + ks * 32 + lg * 8);
        float4 f0 = bp[0], f1 = bp[1];
        union { short8 s; unsigned int u[4]; } t;
        t.u[0] = cvt_pk_bf16(f0.x, f0.y);
        t.u[1] = cvt_pk_bf16(f0.z, f0.w);
        t.u[2] = cvt_pk_bf16(f1.x, f1.y);
        t.u[3] = cvt_pk_bf16(f1.z, f1.w);
        xa[ks] = t.s;
    }

    f32x4 acc[16];
#pragma unroll
    for (int t = 0; t < 16; ++t) {
#pragma unroll
        for (int i = 0; i < 4; ++i)
            acc[t][i] = (t < 8) ? bias1[t * 16 + lg * 4 + i] : 0.f;
    }
#pragma unroll
    for (int ks = 0; ks < 2; ++ks)
#pragma unroll
        for (int t = 0; t < 16; ++t) {
            short8 wf = *reinterpret_cast<const short8*>(Wp + (((ks * 4 + lg) * 256) + t * 16 + lr) * 8);
            acc[t] = __builtin_amdgcn_mfma_f32_16x16x32_bf16(wf, xa[ks], acc[t], 0, 0, 0);
        }
    if (T12) {
        const float* tp = T12 + (long)batch[node] * 256;
#pragma unroll
        for (int t = 0; t < 16; ++t)
#pragma unroll
            for (int i = 0; i < 4; ++i)
                acc[t][i] += tp[t * 16 + lg * 4 + i];
    }
#pragma unroll
    for (int t = 0; t < 16; ++t) {
        uint2 v;
        v.x = cvt_pk_bf16(acc[t][0], acc[t][1]);
        v.y = cvt_pk_bf16(acc[t][2], acc[t][3]);
        *reinterpret_cast<uint2*>(out + (long)node * 256 + t * 16 + lg * 4) = v;
    }
}

// ---------------- global edge pass: hidsum[b][c] += e[dst]*relu(P[dst][c]+Q[src][c]); esum[b] += e[dst] ----------------
// lane l handles channels {2l, 2l+1}; LDS stored de-interleaved (j=l -> ch 2l, j=64+l -> ch 2l+1) for bank-freedom.
__global__ __launch_bounds__(256) void global_edge(
        const ushort* __restrict__ PQ, const int* __restrict__ eidx,
        const float* __restrict__ e, const int* __restrict__ batch,
        float* __restrict__ hidpart, float* __restrict__ esumpart) {
    __shared__ float sAcc[BB * 128];
    __shared__ float sE[BB];
    const int tid = threadIdx.x;
    for (int i = tid; i < BB * 128; i += 256) sAcc[i] = 0.f;
    if (tid < BB) sE[tid] = 0.f;
    __syncthreads();

    const int w = tid >> 6, l = tid & 63;
    const int base = blockIdx.x * 800 + w * 200;

    int nd[4], nsrc[4];
#pragma unroll
    for (int j = 0; j < 4; ++j) { nd[j] = eidx[EE + base + j]; nsrc[j] = eidx[base + j]; }

    for (int it = 0; it < 200; it += 4) {
        int d[4], s[4];
#pragma unroll
        for (int j = 0; j < 4; ++j) { d[j] = nd[j]; s[j] = nsrc[j]; }
        if (it + 4 < 200) {
#pragma unroll
            for (int j = 0; j < 4; ++j) {
                nd[j]   = eidx[EE + base + it + 4 + j];
                nsrc[j] = eidx[base + it + 4 + j];
            }
        }
        unsigned int pd[4], qs[4]; float ev[4]; int bb[4];
#pragma unroll
        for (int j = 0; j < 4; ++j) {
            pd[j] = *reinterpret_cast<const unsigned int*>(PQ + (long)d[j] * 256 + 2 * l);
            qs[j] = *reinterpret_cast<const unsigned int*>(PQ + (long)s[j] * 256 + 128 + 2 * l);
            ev[j] = e[d[j]];
            bb[j] = batch[d[j]];
        }
#pragma unroll
        for (int j = 0; j < 4; ++j) {
            float p0 = __uint_as_float(pd[j] << 16);
            float p1 = __uint_as_float(pd[j] & 0xFFFF0000u);
            float q0 = __uint_as_float(qs[j] << 16);
            float q1 = __uint_as_float(qs[j] & 0xFFFF0000u);
            float h0 = fmaxf(p0 + q0, 0.f) * ev[j];
            float h1 = fmaxf(p1 + q1, 0.f) * ev[j];
            atomicAdd(&sAcc[bb[j] * 128 + l], h0);          // ch 2l
            atomicAdd(&sAcc[bb[j] * 128 + 64 + l], h1);     // ch 2l+1
            if (l == 0) atomicAdd(&sE[bb[j]], ev[j]);
        }
    }
    __syncthreads();
    const int slot = blockIdx.x & (NS - 1);
    float* hp = hidpart + (long)slot * (BB * 128);
    for (int i = tid; i < BB * 128; i += 256) {
        int b = i >> 7, j = i & 127;
        int ch = (j < 64) ? 2 * j : 2 * (j - 64) + 1;
        atomicAdd(&hp[b * 128 + ch], sAcc[i]);
    }
    if (tid < BB) atomicAdd(&esumpart[slot * BB + tid], sE[tid]);
}

// ---------------- pooled[b][c] = hidsum[b]@gW2[:,c] + esum[b]*gb2[c] ----------------
__global__ __launch_bounds__(256) void pooled_kernel(
        const float* __restrict__ hidpart, const float* __restrict__ esumpart,
        const float* __restrict__ gW2, const float* __restrict__ gb2,
        float* __restrict__ pooled) {
    __shared__ float hs[BB * 128];
    __shared__ float es[BB];
    const int tid = threadIdx.x;
    for (int i = tid; i < BB * 128; i += 256) {
        float sum = 0.f;
        for (int s = 0; s < NS; ++s) sum += hidpart[(long)s * (BB * 128) + i];
        hs[i] = sum;
    }
    if (tid < BB) {
        float sum = 0.f;
        for (int s = 0; s < NS; ++s) sum += esumpart[s * BB + tid];
        es[tid] = sum;
    }
    __syncthreads();
    // thread handles 4 float4-column-groups
#pragma unroll
    for (int oo = 0; oo < 4; ++oo) {
        int o4 = tid * 4 + oo;            // 0..1023
        int b = o4 >> 4, c4 = (o4 & 15) * 4;
        float eb = es[b];
        f32x4 acc;
        const float4 gb = *reinterpret_cast<const float4*>(gb2 + c4);
        acc[0] = eb * gb.x; acc[1] = eb * gb.y; acc[2] = eb * gb.z; acc[3] = eb * gb.w;
        for (int k = 0; k < 128; ++k) {
            float hv = hs[b * 128 + k];
            const float4 wv = *reinterpret_cast<const float4*>(gW2 + k * 64 + c4);
            acc[0] += hv * wv.x; acc[1] += hv * wv.y; acc[2] += hv * wv.z; acc[3] += hv * wv.w;
        }
        *reinterpret_cast<f32x4*>(pooled + b * 64 + c4) = acc;
    }
}

// ---------------- T12[b][c2] = pooled[b] @ lW1_scalarpart ----------------
// c2<128: sum_k pooled[b][k]*lW1[64+k][c2]; c2>=128: sum_k pooled[b][k]*lW1[192+k][c2-128]
__global__ __launch_bounds__(256) void t12_kernel(
        const float* __restrict__ pooled, const float* __restrict__ lW1,
        float* __restrict__ T12) {
    __shared__ float pb[64];
    const int b = blockIdx.x, c2 = threadIdx.x;
    if (c2 < 64) pb[c2] = pooled[b * 64 + c2];
    __syncthreads();
    const float* col = (c2 < 128) ? (lW1 + 64 * 128 + c2) : (lW1 + 192 * 128 + (c2 - 128));
    float acc = 0.f;
    for (int k = 0; k < 64; ++k) acc += pb[k] * col[k * 128];
    T12[b * 256 + c2] = acc;
}

// ---------------- local edge pass: out[dst] += relu(PL[dst]+QL[src])·lW2 + lb2 ----------------
// 4 edges per wave-iter; 16 lanes per edge, 8 channels per lane.
__global__ __launch_bounds__(256) void local_edge(
        const ushort* __restrict__ PQL, const int* __restrict__ eidx,
        const float* __restrict__ lW2, const float* __restrict__ lb2,
        float* __restrict__ out) {
    const int tid = threadIdx.x;
    const int w = tid >> 6, l = tid & 63, q = l >> 4, c16 = l & 15;
    float w2r[8];
#pragma unroll
    for (int j = 0; j < 8; ++j) w2r[j] = lW2[c16 * 8 + j];
    const float b2v = lb2[0];
    const int wavebase = (blockIdx.x * 4 + w) * 128;

#pragma unroll 4
    for (int it = 0; it < 32; ++it) {
        const int e0 = wavebase + it * 4 + q;
        const int dst = eidx[EE + e0], src = eidx[e0];
        short8 pd = *reinterpret_cast<const short8*>(PQL + (long)dst * 256 + c16 * 8);
        short8 qsv = *reinterpret_cast<const short8*>(PQL + (long)src * 256 + 128 + c16 * 8);
        float s = 0.f;
#pragma unroll
        for (int j = 0; j < 8; ++j) {
            float pv = bf2f((ushort)pd[j]);
            float qv = bf2f((ushort)qsv[j]);
            s += fmaxf(pv + qv, 0.f) * w2r[j];
        }
        s += __shfl_xor(s, 1, 64);
        s += __shfl_xor(s, 2, 64);
        s += __shfl_xor(s, 4, 64);
        s += __shfl_xor(s, 8, 64);
        if (c16 == 0) atomicAdd(&out[dst], s + b2v);
    }
}

extern "C" void kernel_launch(void* const* d_in, const int* in_sizes, int n_in,
                              void* d_out, int out_size, void* d_ws, size_t ws_size,
                              hipStream_t stream) {
    const float* x   = (const float*)d_in[0];
    const float* e   = (const float*)d_in[1];
    const int*   ei  = (const int*)d_in[2];
    const int*   bat = (const int*)d_in[3];
    const float* gW1 = (const float*)d_in[4];
    const float* gb1 = (const float*)d_in[5];
    const float* gW2 = (const float*)d_in[6];
    const float* gb2 = (const float*)d_in[7];
    const float* lW1 = (const float*)d_in[8];
    const float* lb1 = (const float*)d_in[9];
    const float* lW2 = (const float*)d_in[10];
    const float* lb2 = (const float*)d_in[11];

    char* ws = (char*)d_ws;
    ushort* W1p     = (ushort*)(ws);                     //  32768 B
    ushort* L1p     = (ushort*)(ws + 32768);             //  32768 B
    float*  T12     = (float*)(ws + 65536);              //  65536 B
    float*  pooled  = (float*)(ws + 131072);             //  16384 B
    float*  esumpart= (float*)(ws + 147456);             //   8192 B
    float*  hidpart = (float*)(ws + 155648);             // 1048576 B
    ushort* PQ      = (ushort*)(ws + 1204224);           // 26214400 B (reused for PQL)

    hipMemsetAsync(ws + 147456, 0, 8192 + 1048576, stream);          // esumpart + hidpart
    hipMemsetAsync(d_out, 0, (size_t)out_size * sizeof(float), stream);

    prep_weights<<<1, 512, 0, stream>>>(gW1, lW1, W1p, L1p);
    pq_gemm<<<NN / 128, 512, 0, stream>>>(x, W1p, gb1, nullptr, bat, PQ);
    global_edge<<<1024, 256, 0, stream>>>(PQ, ei, e, bat, hidpart, esumpart);
    pooled_kernel<<<1, 256, 0, stream>>>(hidpart, esumpart, gW2, gb2, pooled);
    t12_kernel<<<BB, 256, 0, stream>>>(pooled, lW1, T12);
    pq_gemm<<<NN / 128, 512, 0, stream>>>(x, L1p, lb1, T12, bat, PQ);   // -> PQL
    local_edge<<<1600, 256, 0, stream>>>(PQ, ei, lW2, lb2, (float*)d_out);
}

// Round 4
// 350.296 us; speedup vs baseline: 2.1592x; 2.0330x over previous
//
#include <hip/hip_runtime.h>
#include <hip/hip_bf16.h>

#define NN 51200
#define EE 819200
#define BB 64
#define NS 32
#define NPW 16   // nodes per wave in edge passes

typedef __attribute__((ext_vector_type(8))) short short8;
typedef __attribute__((ext_vector_type(4))) float f32x4;

__device__ __forceinline__ ushort f2bf(float f) {
    unsigned int u = __float_as_uint(f);
    unsigned int r = (u + 0x7FFFu + ((u >> 16) & 1u)) >> 16;   // RNE, finite inputs
    return (ushort)r;
}
__device__ __forceinline__ unsigned int cvt_pk_bf16(float lo, float hi) {
    unsigned int r;
    asm("v_cvt_pk_bf16_f32 %0, %1, %2" : "=v"(r) : "v"(lo), "v"(hi));
    return r;
}

// ---------------- weight prep ----------------
// W1p: frag-ordered [gW1[0:64] | gW1[64:128]] viewed as [64 k][256 c]
// L1p: frag-ordered [lW1[0:64] | lW1[128:192]] viewed as [64 k][256 c]
__global__ void prep_weights(const float* __restrict__ gW1, const float* __restrict__ lW1,
                             ushort* __restrict__ W1p, ushort* __restrict__ L1p) {
    int tid = threadIdx.x;
    for (int idx = tid; idx < 64 * 256; idx += 512) {
        int i = idx & 7, c = (idx >> 3) & 255, q = idx >> 11;
        int k = (q >> 2) * 32 + (q & 3) * 8 + i;
        W1p[idx] = f2bf(c < 128 ? gW1[k * 128 + c] : gW1[(64 + k) * 128 + (c - 128)]);
        L1p[idx] = f2bf(c < 128 ? lW1[k * 128 + c] : lW1[(128 + k) * 128 + (c - 128)]);
    }
}

// ---------------- CSR build ----------------
__global__ void hist_kernel(const int* __restrict__ eidx, int* __restrict__ cnt) {
    int i = blockIdx.x * 256 + threadIdx.x;
    atomicAdd(&cnt[eidx[EE + i]], 1);
}

__global__ __launch_bounds__(1024) void prefix_kernel(const int* __restrict__ cnt,
                                                      int* __restrict__ offs,
                                                      int* __restrict__ cursor) {
    __shared__ int sps[1024];
    const int t = threadIdx.x;
    const int base = t * 50;            // 51200 / 1024
    int sum = 0;
    for (int j = 0; j < 50; ++j) sum += cnt[base + j];
    sps[t] = sum;
    __syncthreads();
    for (int o = 1; o < 1024; o <<= 1) {
        int v = (t >= o) ? sps[t - o] : 0;
        __syncthreads();
        sps[t] += v;
        __syncthreads();
    }
    int run = sps[t] - sum;             // exclusive prefix
    for (int j = 0; j < 50; ++j) {
        offs[base + j] = run;
        cursor[base + j] = run;
        run += cnt[base + j];
    }
    if (t == 1023) offs[NN] = EE;
}

__global__ void scatter_kernel(const int* __restrict__ eidx, int* __restrict__ cursor,
                               int* __restrict__ csr) {
    int i = blockIdx.x * 256 + threadIdx.x;
    int d = eidx[EE + i], s = eidx[i];
    int pos = atomicAdd(&cursor[d], 1);
    csr[pos] = s;
}

// ---------------- node-table GEMM: out[n][0:256] = bf16( x[n]@Wcat + bias_fold + T12[batch[n]] ) ----------------
__global__ __launch_bounds__(512) void pq_gemm(
        const float* __restrict__ x, const ushort* __restrict__ Wp,
        const float* __restrict__ bias1, const float* __restrict__ T12,
        const int* __restrict__ batch, ushort* __restrict__ out) {
    const int tid = threadIdx.x;
    const int w = tid >> 6, l = tid & 63, lr = l & 15, lg = l >> 4;
    const int node = blockIdx.x * 128 + w * 16 + lr;

    short8 xa[2];
#pragma unroll
    for (int ks = 0; ks < 2; ++ks) {
        const float4* bp = reinterpret_cast<const float4*>(x + (long)node * 64 + ks * 32 + lg * 8);
        float4 f0 = bp[0], f1 = bp[1];
        union { short8 s; unsigned int u[4]; } t;
        t.u[0] = cvt_pk_bf16(f0.x, f0.y);
        t.u[1] = cvt_pk_bf16(f0.z, f0.w);
        t.u[2] = cvt_pk_bf16(f1.x, f1.y);
        t.u[3] = cvt_pk_bf16(f1.z, f1.w);
        xa[ks] = t.s;
    }
    f32x4 acc[16];
#pragma unroll
    for (int t = 0; t < 16; ++t)
#pragma unroll
        for (int i = 0; i < 4; ++i)
            acc[t][i] = (t < 8) ? bias1[t * 16 + lg * 4 + i] : 0.f;
#pragma unroll
    for (int ks = 0; ks < 2; ++ks)
#pragma unroll
        for (int t = 0; t < 16; ++t) {
            short8 wf = *reinterpret_cast<const short8*>(Wp + (((ks * 4 + lg) * 256) + t * 16 + lr) * 8);
            acc[t] = __builtin_amdgcn_mfma_f32_16x16x32_bf16(wf, xa[ks], acc[t], 0, 0, 0);
        }
    if (T12) {
        const float* tp = T12 + (long)batch[node] * 256;
#pragma unroll
        for (int t = 0; t < 16; ++t)
#pragma unroll
            for (int i = 0; i < 4; ++i)
                acc[t][i] += tp[t * 16 + lg * 4 + i];
    }
#pragma unroll
    for (int t = 0; t < 16; ++t) {
        uint2 v;
        v.x = cvt_pk_bf16(acc[t][0], acc[t][1]);
        v.y = cvt_pk_bf16(acc[t][2], acc[t][3]);
        *reinterpret_cast<uint2*>(out + (long)node * 256 + t * 16 + lg * 4) = v;
    }
}

// ---------------- global edge pass (CSR): reg-accumulated pooling ----------------
// wave owns NPW dst nodes; lane l covers channels {2l, 2l+1}
__global__ __launch_bounds__(256) void global_edge(
        const ushort* __restrict__ PQ, const int* __restrict__ csr,
        const int* __restrict__ offs, const float* __restrict__ e,
        const int* __restrict__ batch,
        float* __restrict__ hidpart, float* __restrict__ esumpart) {
    const int tid = threadIdx.x;
    const int w = tid >> 6, l = tid & 63;
    const int wid = blockIdx.x * 4 + w;
    const int node0 = wid * NPW;
    const int slot = wid & (NS - 1);

    const int offv = offs[node0 + ((l < 17) ? l : 16)];
    const float evv = e[node0 + (l & 15)];
    const int bv = batch[node0 + (l & 15)];

    float accp0 = 0.f, accp1 = 0.f, eacc = 0.f;
    int curb = __shfl(bv, 0, 64);

    for (int n = 0; n < NPW; ++n) {
        const int off = __shfl(offv, n, 64);
        const int cnt = __shfl(offv, n + 1, 64) - off;
        const int bb  = __shfl(bv, n, 64);
        const float ev = __shfl(evv, n, 64);
        if (bb != curb) {
            float* hp = hidpart + (long)slot * (BB * 128) + curb * 128;
            atomicAdd(hp + 2 * l, accp0);
            atomicAdd(hp + 2 * l + 1, accp1);
            if (l == 0) atomicAdd(&esumpart[slot * BB + curb], eacc);
            accp0 = accp1 = eacc = 0.f;
            curb = bb;
        }
        if (cnt <= 0) continue;
        const unsigned int pdu = *reinterpret_cast<const unsigned int*>(PQ + (long)(node0 + n) * 256 + 2 * l);
        const float p0 = __uint_as_float(pdu << 16);
        const float p1 = __uint_as_float(pdu & 0xFFFF0000u);
        float h0 = 0.f, h1 = 0.f;
        for (int g0 = 0; g0 < cnt; g0 += 64) {
            int m = cnt - g0; if (m > 64) m = 64;
            const int srcv = csr[off + g0 + ((l < m) ? l : (m - 1))];
            for (int jj = 0; jj < m; jj += 8) {
                unsigned int qv[8];
#pragma unroll
                for (int k = 0; k < 8; ++k) {
                    int kk = jj + k; if (kk > m - 1) kk = m - 1;
                    const int s = __shfl(srcv, kk, 64);
                    qv[k] = *reinterpret_cast<const unsigned int*>(PQ + (long)s * 256 + 128 + 2 * l);
                }
#pragma unroll
                for (int k = 0; k < 8; ++k) {
                    const float q0 = __uint_as_float(qv[k] << 16);
                    const float q1 = __uint_as_float(qv[k] & 0xFFFF0000u);
                    const float r0 = fmaxf(p0 + q0, 0.f);
                    const float r1 = fmaxf(p1 + q1, 0.f);
                    if (jj + k < m) { h0 += r0; h1 += r1; }
                }
            }
        }
        accp0 += ev * h0; accp1 += ev * h1; eacc += ev * (float)cnt;
    }
    {
        float* hp = hidpart + (long)slot * (BB * 128) + curb * 128;
        atomicAdd(hp + 2 * l, accp0);
        atomicAdd(hp + 2 * l + 1, accp1);
        if (l == 0) atomicAdd(&esumpart[slot * BB + curb], eacc);
    }
}

// ---------------- pooled[b][c] = hidsum[b]@gW2[:,c] + esum[b]*gb2[c] ----------------
__global__ __launch_bounds__(256) void pooled_kernel(
        const float* __restrict__ hidpart, const float* __restrict__ esumpart,
        const float* __restrict__ gW2, const float* __restrict__ gb2,
        float* __restrict__ pooled) {
    __shared__ float hs[BB * 128];
    __shared__ float es[BB];
    const int tid = threadIdx.x;
    for (int i = tid; i < BB * 128; i += 256) {
        float sum = 0.f;
        for (int s = 0; s < NS; ++s) sum += hidpart[(long)s * (BB * 128) + i];
        hs[i] = sum;
    }
    if (tid < BB) {
        float sum = 0.f;
        for (int s = 0; s < NS; ++s) sum += esumpart[s * BB + tid];
        es[tid] = sum;
    }
    __syncthreads();
#pragma unroll
    for (int oo = 0; oo < 4; ++oo) {
        int o4 = tid * 4 + oo;
        int b = o4 >> 4, c4 = (o4 & 15) * 4;
        float eb = es[b];
        f32x4 acc;
        const float4 gb = *reinterpret_cast<const float4*>(gb2 + c4);
        acc[0] = eb * gb.x; acc[1] = eb * gb.y; acc[2] = eb * gb.z; acc[3] = eb * gb.w;
        for (int k = 0; k < 128; ++k) {
            float hv = hs[b * 128 + k];
            const float4 wv = *reinterpret_cast<const float4*>(gW2 + k * 64 + c4);
            acc[0] += hv * wv.x; acc[1] += hv * wv.y; acc[2] += hv * wv.z; acc[3] += hv * wv.w;
        }
        *reinterpret_cast<f32x4*>(pooled + b * 64 + c4) = acc;
    }
}

// ---------------- T12[b][c2] = pooled[b] @ lW1_scalarpart ----------------
__global__ __launch_bounds__(256) void t12_kernel(
        const float* __restrict__ pooled, const float* __restrict__ lW1,
        float* __restrict__ T12) {
    __shared__ float pb[64];
    const int b = blockIdx.x, c2 = threadIdx.x;
    if (c2 < 64) pb[c2] = pooled[b * 64 + c2];
    __syncthreads();
    const float* col = (c2 < 128) ? (lW1 + 64 * 128 + c2) : (lW1 + 192 * 128 + (c2 - 128));
    float acc = 0.f;
    for (int k = 0; k < 64; ++k) acc += pb[k] * col[k * 128];
    T12[b * 256 + c2] = acc;
}

// ---------------- local edge pass (CSR): out[n] = sum_src relu(PL[n]+QL[src])·w2 + cnt*b2 ----------------
__global__ __launch_bounds__(256) void local_edge(
        const ushort* __restrict__ PQL, const int* __restrict__ csr,
        const int* __restrict__ offs, const float* __restrict__ lW2,
        const float* __restrict__ lb2, float* __restrict__ out) {
    const int tid = threadIdx.x;
    const int w = tid >> 6, l = tid & 63;
    const int wid = blockIdx.x * 4 + w;
    const int node0 = wid * NPW;
    const int offv = offs[node0 + ((l < 17) ? l : 16)];
    const float w20 = lW2[2 * l], w21 = lW2[2 * l + 1];
    const float b2v = lb2[0];

    for (int n = 0; n < NPW; ++n) {
        const int off = __shfl(offv, n, 64);
        const int cnt = __shfl(offv, n + 1, 64) - off;
        float dacc = 0.f;
        if (cnt > 0) {
            const unsigned int pdu = *reinterpret_cast<const unsigned int*>(PQL + (long)(node0 + n) * 256 + 2 * l);
            const float p0 = __uint_as_float(pdu << 16);
            const float p1 = __uint_as_float(pdu & 0xFFFF0000u);
            for (int g0 = 0; g0 < cnt; g0 += 64) {
                int m = cnt - g0; if (m > 64) m = 64;
                const int srcv = csr[off + g0 + ((l < m) ? l : (m - 1))];
                for (int jj = 0; jj < m; jj += 8) {
                    unsigned int qv[8];
#pragma unroll
                    for (int k = 0; k < 8; ++k) {
                        int kk = jj + k; if (kk > m - 1) kk = m - 1;
                        const int s = __shfl(srcv, kk, 64);
                        qv[k] = *reinterpret_cast<const unsigned int*>(PQL + (long)s * 256 + 128 + 2 * l);
                    }
#pragma unroll
                    for (int k = 0; k < 8; ++k) {
                        const float q0 = __uint_as_float(qv[k] << 16);
                        const float q1 = __uint_as_float(qv[k] & 0xFFFF0000u);
                        const float t0 = fmaxf(p0 + q0, 0.f) * w20 + fmaxf(p1 + q1, 0.f) * w21;
                        if (jj + k < m) dacc += t0;
                    }
                }
            }
            dacc += __shfl_xor(dacc, 1, 64);
            dacc += __shfl_xor(dacc, 2, 64);
            dacc += __shfl_xor(dacc, 4, 64);
            dacc += __shfl_xor(dacc, 8, 64);
            dacc += __shfl_xor(dacc, 16, 64);
            dacc += __shfl_xor(dacc, 32, 64);
        }
        if (l == 0) out[node0 + n] = dacc + (float)cnt * b2v;
    }
}

extern "C" void kernel_launch(void* const* d_in, const int* in_sizes, int n_in,
                              void* d_out, int out_size, void* d_ws, size_t ws_size,
                              hipStream_t stream) {
    const float* x   = (const float*)d_in[0];
    const float* e   = (const float*)d_in[1];
    const int*   ei  = (const int*)d_in[2];
    const int*   bat = (const int*)d_in[3];
    const float* gW1 = (const float*)d_in[4];
    const float* gb1 = (const float*)d_in[5];
    const float* gW2 = (const float*)d_in[6];
    const float* gb2 = (const float*)d_in[7];
    const float* lW1 = (const float*)d_in[8];
    const float* lb1 = (const float*)d_in[9];
    const float* lW2 = (const float*)d_in[10];
    const float* lb2 = (const float*)d_in[11];

    char* ws = (char*)d_ws;
    ushort* W1p     = (ushort*)(ws);                     //    32768 B
    ushort* L1p     = (ushort*)(ws + 32768);             //    32768 B
    float*  T12     = (float*)(ws + 65536);              //    65536 B
    float*  pooled  = (float*)(ws + 131072);             //    16384 B
    float*  esumpart= (float*)(ws + 147456);             //     8192 B
    float*  hidpart = (float*)(ws + 155648);             //  1048576 B
    int*    counts  = (int*)(ws + 1204224);              //   204800 B
    int*    offs    = (int*)(ws + 1409024);              //   204816 B (51201 ints)
    int*    cursor  = (int*)(ws + 1613840);              //   204800 B
    int*    csr     = (int*)(ws + 1818640);              //  3276800 B
    ushort* PQ      = (ushort*)(ws + 5095440);           // 26214400 B (reused for PQL)

    hipMemsetAsync(counts, 0, 204800, stream);
    hipMemsetAsync(esumpart, 0, 8192 + 1048576, stream);           // esumpart + hidpart
    hipMemsetAsync(d_out, 0, (size_t)out_size * sizeof(float), stream);

    prep_weights<<<1, 512, 0, stream>>>(gW1, lW1, W1p, L1p);
    hist_kernel<<<EE / 256, 256, 0, stream>>>(ei, counts);
    prefix_kernel<<<1, 1024, 0, stream>>>(counts, offs, cursor);
    scatter_kernel<<<EE / 256, 256, 0, stream>>>(ei, cursor, csr);

    pq_gemm<<<NN / 128, 512, 0, stream>>>(x, W1p, gb1, nullptr, bat, PQ);
    global_edge<<<NN / (4 * NPW), 256, 0, stream>>>(PQ, csr, offs, e, bat, hidpart, esumpart);
    pooled_kernel<<<1, 256, 0, stream>>>(hidpart, esumpart, gW2, gb2, pooled);
    t12_kernel<<<BB, 256, 0, stream>>>(pooled, lW1, T12);
    pq_gemm<<<NN / 128, 512, 0, stream>>>(x, L1p, lb1, T12, bat, PQ);   // -> PQL
    local_edge<<<NN / (4 * NPW), 256, 0, stream>>>(PQ, csr, offs, lW2, lb2, (float*)d_out);
}